// Round 19
// baseline (563.203 us; speedup 1.0000x reference)
//
#include <hip/hip_runtime.h>
#include <hip/hip_bf16.h>
#include <math.h>

#define EMBED 4096
#define SLEN 2048
#define HEADS 16
#define HDIM 256
#define ROT 64

typedef __bf16 bf16;
typedef __attribute__((ext_vector_type(8))) __bf16 bf16x8;
typedef __attribute__((ext_vector_type(4))) float f32x4;

__device__ __forceinline__ void async_copy16(const void* g, void* l) {
  __builtin_amdgcn_global_load_lds((const __attribute__((address_space(1))) void*)g,
                                   (__attribute__((address_space(3))) void*)l,
                                   16, 0, 0);
}

// ---------------- cast fp32 -> bf16 ----------------
__global__ __launch_bounds__(256) void cast_kernel(const float* __restrict__ in,
                                                   bf16* __restrict__ out, int n4) {
  int i = blockIdx.x * 256 + threadIdx.x;
  if (i >= n4) return;
  float4 v = ((const float4*)in)[i];
  bf16 o[4] __attribute__((aligned(8)));
  o[0] = (bf16)v.x; o[1] = (bf16)v.y; o[2] = (bf16)v.z; o[3] = (bf16)v.w;
  ((ushort4*)out)[i] = *(const ushort4*)o;
}

// ---------------- transpose + cast: Wt[n][k] = W[k][n] ----------------
__device__ __forceinline__ void transpose_body(const float* __restrict__ W,
                                               bf16* __restrict__ Wt) {
  __shared__ bf16 tile[64][65];
  int k0 = blockIdx.y * 64, n0 = blockIdx.x * 64;
  int tr = threadIdx.x >> 4, tc = threadIdx.x & 15;
#pragma unroll
  for (int i = 0; i < 4; i++) {
    int row = tr + i * 16;
    float4 v = *(const float4*)(W + (size_t)(k0 + row) * EMBED + n0 + tc * 4);
    tile[row][tc * 4 + 0] = (bf16)v.x;
    tile[row][tc * 4 + 1] = (bf16)v.y;
    tile[row][tc * 4 + 2] = (bf16)v.z;
    tile[row][tc * 4 + 3] = (bf16)v.w;
  }
  __syncthreads();
#pragma unroll
  for (int i = 0; i < 4; i++) {
    int nl = tr + i * 16;
    bf16 o[4] __attribute__((aligned(8)));
#pragma unroll
    for (int j = 0; j < 4; j++) o[j] = tile[tc * 4 + j][nl];
    *(ushort4*)(Wt + (size_t)(n0 + nl) * EMBED + k0 + tc * 4) = *(const ushort4*)o;
  }
}

__global__ __launch_bounds__(256) void transpose_cast(const float* __restrict__ W,
                                                      bf16* __restrict__ Wt) {
  transpose_body(W, Wt);
}

__global__ __launch_bounds__(256) void transpose_cast3(const float* __restrict__ Wq,
                                                       const float* __restrict__ Wk,
                                                       const float* __restrict__ Wv,
                                                       bf16* __restrict__ Wt3) {
  int z = blockIdx.z;
  const float* W = (z == 0) ? Wq : (z == 1) ? Wk : Wv;
  transpose_body(W, Wt3 + (size_t)z * EMBED * EMBED);
}

__global__ __launch_bounds__(256) void transpose_cast4(const float* __restrict__ Wq,
                                                       const float* __restrict__ Wk,
                                                       const float* __restrict__ Wv,
                                                       const float* __restrict__ Wo,
                                                       bf16* __restrict__ Wt4) {
  int z = blockIdx.z;
  const float* W = (z == 0) ? Wq : (z == 1) ? Wk : (z == 2) ? Wv : Wo;
  transpose_body(W, Wt4 + (size_t)z * EMBED * EMBED);
}

// ---------------- pipelined GEMM core (R13-proven, 128x256) -------------------
// BM=128, BN=256, BK=64; 512 threads = 8 waves (2M x 4N), 64x64 per wave.
// Triple-buffered LDS (144 KB), prefetch depth 2, ONE barrier per K-tile,
// counted vmcnt(6), XOR swizzle (conflicts=0).
// mode 1: rotary bf16 out (Q,K); 2: V-transposed bf16 out; 3: fp32 out.
__device__ __forceinline__ void gemm_body(const bf16* __restrict__ A,
                                          const bf16* __restrict__ Bt,
                                          void* __restrict__ Cout,
                                          int M, int N, int K, int mode,
                                          int bx, int by) {
  constexpr int BM = 128, BN = 256, BK = 64;
  __shared__ __align__(16) bf16 As[3][BM * BK];  // 3 x 16 KB
  __shared__ __align__(16) bf16 Bs[3][BN * BK];  // 3 x 32 KB
  int t = threadIdx.x;
  int lane = t & 63, w = t >> 6;
  int c16 = lane & 15, g4 = lane >> 4;
  int wm = w >> 2, wn = w & 3;
  int m0 = by * BM, n0 = bx * BN;
  int nt = K / BK;

  f32x4 acc[4][4] = {};

  auto stage = [&](int kt, int slot) {
    const bf16* Asrc = A + (size_t)m0 * K + kt * BK;
    const bf16* Bsrc = Bt + (size_t)n0 * K + kt * BK;
    bf16* Ad = As[slot];
    bf16* Bd = Bs[slot];
#pragma unroll
    for (int i = 0; i < 2; i++) {
      int c = i * 512 + t;
      int row = c >> 3, col8 = c & 7;
      async_copy16(Asrc + (size_t)row * K + ((col8 ^ (row & 7)) * 8), Ad + c * 8);
    }
#pragma unroll
    for (int i = 0; i < 4; i++) {
      int c = i * 512 + t;
      int row = c >> 3, col8 = c & 7;
      async_copy16(Bsrc + (size_t)row * K + ((col8 ^ (row & 7)) * 8), Bd + c * 8);
    }
  };

  stage(0, 0);
  stage(1, 1);
  asm volatile("s_waitcnt vmcnt(6)" ::: "memory");
  __builtin_amdgcn_s_barrier();

  for (int kt = 0; kt < nt; kt++) {
    int slot = kt - (kt / 3) * 3;
    const bf16* Ab = As[slot];
    const bf16* Bb = Bs[slot];

    bf16x8 af[2][4], bfr[2][4];
#pragma unroll
    for (int kk = 0; kk < 2; kk++) {
#pragma unroll
      for (int fm = 0; fm < 4; fm++) {
        int row = wm * 64 + fm * 16 + c16;
        af[kk][fm] = *(const bf16x8*)(Ab + row * BK + (((kk * 4 + g4) ^ (row & 7)) * 8));
      }
#pragma unroll
      for (int fn = 0; fn < 4; fn++) {
        int row = wn * 64 + fn * 16 + c16;
        bfr[kk][fn] = *(const bf16x8*)(Bb + row * BK + (((kk * 4 + g4) ^ (row & 7)) * 8));
      }
    }
    if (kt + 2 < nt) {
      int s2 = (kt + 2) - ((kt + 2) / 3) * 3;
      stage(kt + 2, s2);
    }
    __builtin_amdgcn_s_setprio(1);
#pragma unroll
    for (int kk = 0; kk < 2; kk++)
#pragma unroll
      for (int fm = 0; fm < 4; fm++)
#pragma unroll
        for (int fn = 0; fn < 4; fn++)
          acc[fm][fn] = __builtin_amdgcn_mfma_f32_16x16x32_bf16(af[kk][fm], bfr[kk][fn],
                                                                acc[fm][fn], 0, 0, 0);
    __builtin_amdgcn_s_setprio(0);
    if (kt < nt - 2) {
      asm volatile("s_waitcnt vmcnt(6)" ::: "memory");
      __builtin_amdgcn_s_barrier();
    } else if (kt == nt - 2) {
      asm volatile("s_waitcnt vmcnt(0)" ::: "memory");
      __builtin_amdgcn_s_barrier();
    }
  }

#pragma unroll
  for (int fm = 0; fm < 4; fm++) {
#pragma unroll
    for (int fn = 0; fn < 4; fn++) {
      int col = n0 + wn * 64 + fn * 16 + c16;
#pragma unroll
      for (int r = 0; r < 4; r++) {
        int row = m0 + wm * 64 + fm * 16 + g4 * 4 + r;
        float v = acc[fm][fn][r];
        if (mode == 1) {
          int d = col & (HDIM - 1);
          if (d < ROT) {  // wave-uniform: true iff wn==0
            float pv = __shfl_xor(v, 1);
            int jj = d >> 1;
            float invf = __expf(-0.28782313662425575f * (float)jj);
            float ang = (float)row * invf;
            float sa, ca;
            sincosf(ang, &sa, &ca);
            v = v * ca + pv * sa;  // reference has NO negation in rotate_every_two
          }
        }
        if (mode == 3) {
          ((float*)Cout)[(size_t)row * N + col] = v;
        } else if (mode == 2) {
          ((bf16*)Cout)[(size_t)col * M + row] = (bf16)v;
        } else {
          ((bf16*)Cout)[(size_t)row * N + col] = (bf16)v;
        }
      }
    }
  }
}

template <int MODE>
__global__ __launch_bounds__(512, 1) void gemm_pipe(const bf16* __restrict__ A,
                                                    const bf16* __restrict__ Bt,
                                                    void* __restrict__ Cout,
                                                    int M, int N, int K) {
  int l = blockIdx.x + 16 * blockIdx.y;
  int xcd = l & 7, i = l >> 3;
  int p = i >> 4, by = i & 15;
  int bx = xcd * 2 + p;
  gemm_body(A, Bt, Cout, M, N, K, MODE, bx, by);
}

// ---------------- merged QKV GEMM, 256x256 tiles (R19) ------------------------
// BM=BN=256, BK=64; 512 threads = 8 waves (2M x 4N), per-wave 128x64
// (acc = 8x4 f32x4 = 128 VGPR; ~2x arithmetic intensity of 128x256 -> each
// vmcnt drain amortized over 2x MFMA; block LDS reads/FLOP -25%).
// 2-slot double buffer (128 KB LDS): stage(kt+1) issued FIRST, one
// vmcnt(0)+barrier per tile (R14-proven schedule; drain now covered by the
// 2x longer compute phase). XOR swizzle. Grid (16,8,3) = 384 blocks (75% fill
// -> net predicted +15-20% on QKV; only the merged QKV has enough blocks for
// 256^2 tiles). z -> {weight, output, epilogue mode}.
__global__ __launch_bounds__(512, 1) void gemm_qkv(const bf16* __restrict__ A,
                                                   const bf16* __restrict__ Wt3,
                                                   bf16* __restrict__ Qb,
                                                   bf16* __restrict__ Kb,
                                                   bf16* __restrict__ Vtb) {
  constexpr int BM = 256, BN = 256, BK = 64;
  constexpr int M = SLEN, N = EMBED, K = EMBED;
  __shared__ __align__(16) bf16 As[2][BM * BK];  // 2 x 32 KB
  __shared__ __align__(16) bf16 Bs[2][BN * BK];  // 2 x 32 KB
  int z = blockIdx.z;
  const bf16* Bt = Wt3 + (size_t)z * EMBED * EMBED;
  void* Cout = (z == 0) ? (void*)Qb : (z == 1) ? (void*)Kb : (void*)Vtb;
  int mode = (z == 2) ? 2 : 1;

  int t = threadIdx.x;
  int lane = t & 63, w = t >> 6;
  int c16 = lane & 15, g4 = lane >> 4;
  int wm = w >> 2, wn = w & 3;           // 2M x 4N; per-wave 128 x 64
  int m0 = blockIdx.y * BM, n0 = blockIdx.x * BN;
  int nt = K / BK;

  f32x4 acc[8][4] = {};

  auto stage = [&](int kt, int slot) {
    const bf16* Asrc = A + (size_t)m0 * K + kt * BK;
    const bf16* Bsrc = Bt + (size_t)n0 * K + kt * BK;
    bf16* Ad = As[slot];
    bf16* Bd = Bs[slot];
#pragma unroll
    for (int i = 0; i < 4; i++) {  // A: 2048 chunks / 512 threads
      int c = i * 512 + t;
      int row = c >> 3, col8 = c & 7;
      async_copy16(Asrc + (size_t)row * K + ((col8 ^ (row & 7)) * 8), Ad + c * 8);
    }
#pragma unroll
    for (int i = 0; i < 4; i++) {  // B: 2048 chunks / 512 threads
      int c = i * 512 + t;
      int row = c >> 3, col8 = c & 7;
      async_copy16(Bsrc + (size_t)row * K + ((col8 ^ (row & 7)) * 8), Bd + c * 8);
    }
  };

  // prologue: tile 0 resident
  stage(0, 0);
  asm volatile("s_waitcnt vmcnt(0)" ::: "memory");
  __builtin_amdgcn_s_barrier();

  for (int kt = 0; kt < nt; kt++) {
    int slot = kt & 1;
    // issue next tile FIRST: full 128-MFMA compute phase to land under
    if (kt + 1 < nt) stage(kt + 1, slot ^ 1);
    const bf16* Ab = As[slot];
    const bf16* Bb = Bs[slot];

#pragma unroll
    for (int kk = 0; kk < 2; kk++) {
      bf16x8 bfr[4];
#pragma unroll
      for (int fn = 0; fn < 4; fn++) {
        int row = wn * 64 + fn * 16 + c16;
        bfr[fn] = *(const bf16x8*)(Bb + row * BK + (((kk * 4 + g4) ^ (row & 7)) * 8));
      }
      __builtin_amdgcn_s_setprio(1);
#pragma unroll
      for (int fm = 0; fm < 8; fm++) {
        int row = wm * 128 + fm * 16 + c16;
        bf16x8 afm = *(const bf16x8*)(Ab + row * BK + (((kk * 4 + g4) ^ (row & 7)) * 8));
#pragma unroll
        for (int fn = 0; fn < 4; fn++)
          acc[fm][fn] = __builtin_amdgcn_mfma_f32_16x16x32_bf16(afm, bfr[fn],
                                                                acc[fm][fn], 0, 0, 0);
      }
      __builtin_amdgcn_s_setprio(0);
    }
    // tile kt+1 must be resident; slot hazard: slot^1 overwritten only after
    // the NEXT barrier, by which time all its ds_reads are done.
    asm volatile("s_waitcnt vmcnt(0)" ::: "memory");
    __builtin_amdgcn_s_barrier();
  }

  // epilogue
#pragma unroll
  for (int fm = 0; fm < 8; fm++) {
#pragma unroll
    for (int fn = 0; fn < 4; fn++) {
      int col = n0 + wn * 64 + fn * 16 + c16;
#pragma unroll
      for (int r = 0; r < 4; r++) {
        int row = m0 + wm * 128 + fm * 16 + g4 * 4 + r;
        float v = acc[fm][fn][r];
        if (mode == 1) {
          int d = col & (HDIM - 1);
          if (d < ROT) {  // wave-uniform: true iff wn==0
            float pv = __shfl_xor(v, 1);
            int jj = d >> 1;
            float invf = __expf(-0.28782313662425575f * (float)jj);
            float ang = (float)row * invf;
            float sa, ca;
            sincosf(ang, &sa, &ca);
            v = v * ca + pv * sa;
          }
        }
        if (mode == 2) {
          ((bf16*)Cout)[(size_t)col * M + row] = (bf16)v;
        } else {
          ((bf16*)Cout)[(size_t)row * N + col] = (bf16)v;
        }
      }
    }
  }
}

// ---------------- causal flash attention (R16-proven, unchanged) --------------
__global__ __launch_bounds__(256, 2) void attn_kernel(const bf16* __restrict__ Q,
                                                      const bf16* __restrict__ Kmat,
                                                      const bf16* __restrict__ Vt,
                                                      bf16* __restrict__ O) {
  __shared__ __align__(16) bf16 Ks[64 * 256];
  __shared__ __align__(16) bf16 Vs[64 * 256];
  __shared__ __align__(16) bf16 Pl[4][16 * 64];
  int t = threadIdx.x, lane = t & 63, w = t >> 6;
  int c16 = lane & 15, g4 = lane >> 4;
  int b = blockIdx.x;
  int bb = b & 255;
  int h = bb & 15;
  int k = bb >> 4;
  int qt = (b >> 8) ? k : (31 - k);
  int q0w = qt * 64 + w * 16;

  auto stageK = [&](int kt) {
#pragma unroll
    for (int j = 0; j < 8; j++) {
      int c = j * 256 + t;
      int row = c >> 5, col8 = c & 31;
      async_copy16(Kmat + (size_t)(kt * 64 + row) * EMBED + h * HDIM +
                       ((col8 ^ (row & 7)) * 8),
                   Ks + (size_t)c * 8);
    }
  };
  auto stageV = [&](int kt) {
#pragma unroll
    for (int j = 0; j < 8; j++) {
      int c = j * 256 + t;
      int row = c >> 3, col8 = c & 7;
      async_copy16(Vt + (size_t)(h * HDIM + row) * SLEN + kt * 64 +
                       ((col8 ^ (row & 7)) * 8),
                   Vs + (size_t)c * 8);
    }
  };

  bf16x8 qf[8];
  {
    const bf16* qp = Q + (size_t)(q0w + c16) * EMBED + h * HDIM + g4 * 8;
#pragma unroll
    for (int kk = 0; kk < 8; kk++) qf[kk] = *(const bf16x8*)(qp + kk * 32);
  }
  f32x4 acco[16] = {};
  float mrow[4], lrow[4];
#pragma unroll
  for (int r = 0; r < 4; r++) { mrow[r] = -1e30f; lrow[r] = 0.f; }

  stageK(0);
  stageV(0);
  __syncthreads();

  for (int kt = 0; kt <= qt; kt++) {
    f32x4 accs[4] = {};
    __builtin_amdgcn_s_setprio(1);
#pragma unroll
    for (int kk = 0; kk < 8; kk++) {
#pragma unroll
      for (int fn = 0; fn < 4; fn++) {
        int r = fn * 16 + c16;
        bf16x8 kf = *(const bf16x8*)(Ks + r * 256 + ((kk * 4 + g4) ^ (c16 & 7)) * 8);
        accs[fn] = __builtin_amdgcn_mfma_f32_16x16x32_bf16(qf[kk], kf, accs[fn], 0, 0, 0);
      }
    }
    __builtin_amdgcn_s_setprio(0);
    __syncthreads();
    if (kt < qt) stageK(kt + 1);

    float pm[4][4];
    bool diag = (kt == qt);
#pragma unroll
    for (int fn = 0; fn < 4; fn++)
#pragma unroll
      for (int r = 0; r < 4; r++) {
        float s = accs[fn][r] * 0.0625f;
        if (diag) {
          int kg = fn * 16 + c16;
          int qg = w * 16 + g4 * 4 + r;
          if (kg > qg) s = -1e30f;
        }
        pm[fn][r] = s;
      }
    float lmax[4];
#pragma unroll
    for (int r = 0; r < 4; r++)
      lmax[r] = fmaxf(fmaxf(pm[0][r], pm[1][r]), fmaxf(pm[2][r], pm[3][r]));
    bool need = false;
#pragma unroll
    for (int r = 0; r < 4; r++) need = need || (lmax[r] > mrow[r] + 8.0f);
    if (__any(need)) {
#pragma unroll
      for (int r = 0; r < 4; r++) {
        float mx = lmax[r];
#pragma unroll
        for (int off = 1; off < 16; off <<= 1) mx = fmaxf(mx, __shfl_xor(mx, off));
        float mn = fmaxf(mrow[r], mx);
        float sc = __expf(mrow[r] - mn);
        mrow[r] = mn;
        lrow[r] *= sc;
#pragma unroll
        for (int fd = 0; fd < 16; fd++) acco[fd][r] *= sc;
      }
    }
#pragma unroll
    for (int fn = 0; fn < 4; fn++)
#pragma unroll
      for (int r = 0; r < 4; r++) {
        float p = __expf(pm[fn][r] - mrow[r]);
        pm[fn][r] = p;
        lrow[r] += p;
      }
#pragma unroll
    for (int fn = 0; fn < 4; fn++)
#pragma unroll
      for (int r = 0; r < 4; r++) {
        int q = g4 * 4 + r;
        int chunk = (fn * 2 + (c16 >> 3)) ^ (q & 7);
        Pl[w][q * 64 + chunk * 8 + (c16 & 7)] = (bf16)pm[fn][r];
      }
    __builtin_amdgcn_s_setprio(1);
#pragma unroll
    for (int kk2 = 0; kk2 < 2; kk2++) {
      bf16x8 pf = *(const bf16x8*)(&Pl[w][c16 * 64 + ((kk2 * 4 + g4) ^ (c16 & 7)) * 8]);
#pragma unroll
      for (int fd = 0; fd < 16; fd++) {
        int rv = fd * 16 + c16;
        bf16x8 vf = *(const bf16x8*)(Vs + rv * 64 + ((kk2 * 4 + g4) ^ (c16 & 7)) * 8);
        acco[fd] = __builtin_amdgcn_mfma_f32_16x16x32_bf16(pf, vf, acco[fd], 0, 0, 0);
      }
    }
    __builtin_amdgcn_s_setprio(0);
    __syncthreads();
    if (kt < qt) stageV(kt + 1);
  }
  float inv[4];
#pragma unroll
  for (int r = 0; r < 4; r++) {
    float s = lrow[r];
#pragma unroll
    for (int off = 1; off < 16; off <<= 1) s += __shfl_xor(s, off);
    inv[r] = 1.0f / s;
  }
#pragma unroll
  for (int fd = 0; fd < 16; fd++)
#pragma unroll
    for (int r = 0; r < 4; r++) {
      int qg = q0w + g4 * 4 + r;
      int col = h * HDIM + fd * 16 + c16;
      O[(size_t)qg * EMBED + col] = (bf16)(acco[fd][r] * inv[r]);
    }
}

extern "C" void kernel_launch(void* const* d_in, const int* in_sizes, int n_in,
                              void* d_out, int out_size, void* d_ws, size_t ws_size,
                              hipStream_t stream) {
  const float* hidden = (const float*)d_in[0];
  const float* Wq = (const float*)d_in[1];
  const float* Wk = (const float*)d_in[2];
  const float* Wv = (const float*)d_in[3];
  const float* Wo = (const float*)d_in[4];
  float* out = (float*)d_out;

  char* ws = (char*)d_ws;
  const size_t SZ_H = (size_t)SLEN * EMBED * 2;   // 16 MiB
  const size_t SZ_W = (size_t)EMBED * EMBED * 2;  // 32 MiB

  dim3 tgrid(EMBED / 64, EMBED / 64);
  dim3 ggrid(EMBED / 256, SLEN / 128);  // 16 x 16 = 256 blocks
  dim3 qgrid(EMBED / 256, SLEN / 256, 3);  // 16 x 8 x 3 = 384 blocks (256^2)

  if (ws_size >= 5 * SZ_H + 4 * SZ_W) {
    // fully merged path (208 MiB)
    bf16* h_bf = (bf16*)ws;
    bf16* Wt4  = (bf16*)(ws + SZ_H);
    bf16* Qb   = (bf16*)(ws + SZ_H + 4 * SZ_W);
    bf16* Kb   = (bf16*)(ws + 2 * SZ_H + 4 * SZ_W);
    bf16* Vtb  = (bf16*)(ws + 3 * SZ_H + 4 * SZ_W);
    bf16* Ob   = (bf16*)(ws + 4 * SZ_H + 4 * SZ_W);

    cast_kernel<<<(SLEN * EMBED / 4 + 255) / 256, 256, 0, stream>>>(
        hidden, h_bf, SLEN * EMBED / 4);
    transpose_cast4<<<dim3(EMBED / 64, EMBED / 64, 4), 256, 0, stream>>>(
        Wq, Wk, Wv, Wo, Wt4);
    gemm_qkv<<<qgrid, 512, 0, stream>>>(h_bf, Wt4, Qb, Kb, Vtb);
    attn_kernel<<<dim3(512), 256, 0, stream>>>(Qb, Kb, Vtb, Ob);
    gemm_pipe<3><<<ggrid, 512, 0, stream>>>(Ob, Wt4 + (size_t)3 * EMBED * EMBED,
                                            out, SLEN, EMBED, EMBED);
    return;
  }

  if (ws_size >= 5 * SZ_H + 3 * SZ_W) {
    // merged path (176 MiB)
    bf16* h_bf = (bf16*)ws;
    bf16* Wt3  = (bf16*)(ws + SZ_H);
    bf16* Qb   = (bf16*)(ws + SZ_H + 3 * SZ_W);
    bf16* Kb   = (bf16*)(ws + 2 * SZ_H + 3 * SZ_W);
    bf16* Vtb  = (bf16*)(ws + 3 * SZ_H + 3 * SZ_W);
    bf16* Ob   = (bf16*)(ws + 4 * SZ_H + 3 * SZ_W);

    cast_kernel<<<(SLEN * EMBED / 4 + 255) / 256, 256, 0, stream>>>(
        hidden, h_bf, SLEN * EMBED / 4);
    transpose_cast3<<<dim3(EMBED / 64, EMBED / 64, 3), 256, 0, stream>>>(Wq, Wk,
                                                                         Wv, Wt3);
    gemm_qkv<<<qgrid, 512, 0, stream>>>(h_bf, Wt3, Qb, Kb, Vtb);
    attn_kernel<<<dim3(512), 256, 0, stream>>>(Qb, Kb, Vtb, Ob);
    transpose_cast<<<tgrid, 256, 0, stream>>>(Wo, Wt3);
    gemm_pipe<3><<<ggrid, 512, 0, stream>>>(Ob, Wt3, out, SLEN, EMBED, EMBED);
    return;
  }

  // fallback (112 MiB) — per-GEMM path with 128x256 kernels
  if (ws_size < 5 * SZ_H + SZ_W) return;
  bf16* h_bf = (bf16*)ws;
  bf16* Wt   = (bf16*)(ws + SZ_H);
  bf16* Qb   = (bf16*)(ws + SZ_H + SZ_W);
  bf16* Kb   = (bf16*)(ws + 2 * SZ_H + SZ_W);
  bf16* Vtb  = (bf16*)(ws + 3 * SZ_H + SZ_W);
  bf16* Ob   = (bf16*)(ws + 4 * SZ_H + SZ_W);

  cast_kernel<<<(SLEN * EMBED / 4 + 255) / 256, 256, 0, stream>>>(hidden, h_bf,
                                                                  SLEN * EMBED / 4);
  transpose_cast<<<tgrid, 256, 0, stream>>>(Wq, Wt);
  gemm_pipe<1><<<ggrid, 512, 0, stream>>>(h_bf, Wt, Qb, SLEN, EMBED, EMBED);
  transpose_cast<<<tgrid, 256, 0, stream>>>(Wk, Wt);
  gemm_pipe<1><<<ggrid, 512, 0, stream>>>(h_bf, Wt, Kb, SLEN, EMBED, EMBED);
  transpose_cast<<<tgrid, 256, 0, stream>>>(Wv, Wt);
  gemm_pipe<2><<<ggrid, 512, 0, stream>>>(h_bf, Wt, Vtb, SLEN, EMBED, EMBED);
  attn_kernel<<<dim3(512), 256, 0, stream>>>(Qb, Kb, Vtb, Ob);
  transpose_cast<<<tgrid, 256, 0, stream>>>(Wo, Wt);
  gemm_pipe<3><<<ggrid, 512, 0, stream>>>(Ob, Wt, out, SLEN, EMBED, EMBED);
}

// Round 20
// 451.135 us; speedup vs baseline: 1.2484x; 1.2484x over previous
//
#include <hip/hip_runtime.h>
#include <hip/hip_bf16.h>
#include <math.h>

#define EMBED 4096
#define SLEN 2048
#define HEADS 16
#define HDIM 256
#define ROT 64

typedef __bf16 bf16;
typedef __attribute__((ext_vector_type(8))) __bf16 bf16x8;
typedef __attribute__((ext_vector_type(4))) float f32x4;

__device__ __forceinline__ void async_copy16(const void* g, void* l) {
  __builtin_amdgcn_global_load_lds((const __attribute__((address_space(1))) void*)g,
                                   (__attribute__((address_space(3))) void*)l,
                                   16, 0, 0);
}

// ---------------- cast fp32 -> bf16 ----------------
__global__ __launch_bounds__(256) void cast_kernel(const float* __restrict__ in,
                                                   bf16* __restrict__ out, int n4) {
  int i = blockIdx.x * 256 + threadIdx.x;
  if (i >= n4) return;
  float4 v = ((const float4*)in)[i];
  bf16 o[4] __attribute__((aligned(8)));
  o[0] = (bf16)v.x; o[1] = (bf16)v.y; o[2] = (bf16)v.z; o[3] = (bf16)v.w;
  ((ushort4*)out)[i] = *(const ushort4*)o;
}

// ---------------- transpose + cast: Wt[n][k] = W[k][n] ----------------
__device__ __forceinline__ void transpose_body(const float* __restrict__ W,
                                               bf16* __restrict__ Wt) {
  __shared__ bf16 tile[64][65];
  int k0 = blockIdx.y * 64, n0 = blockIdx.x * 64;
  int tr = threadIdx.x >> 4, tc = threadIdx.x & 15;
#pragma unroll
  for (int i = 0; i < 4; i++) {
    int row = tr + i * 16;
    float4 v = *(const float4*)(W + (size_t)(k0 + row) * EMBED + n0 + tc * 4);
    tile[row][tc * 4 + 0] = (bf16)v.x;
    tile[row][tc * 4 + 1] = (bf16)v.y;
    tile[row][tc * 4 + 2] = (bf16)v.z;
    tile[row][tc * 4 + 3] = (bf16)v.w;
  }
  __syncthreads();
#pragma unroll
  for (int i = 0; i < 4; i++) {
    int nl = tr + i * 16;
    bf16 o[4] __attribute__((aligned(8)));
#pragma unroll
    for (int j = 0; j < 4; j++) o[j] = tile[tc * 4 + j][nl];
    *(ushort4*)(Wt + (size_t)(n0 + nl) * EMBED + k0 + tc * 4) = *(const ushort4*)o;
  }
}

__global__ __launch_bounds__(256) void transpose_cast(const float* __restrict__ W,
                                                      bf16* __restrict__ Wt) {
  transpose_body(W, Wt);
}

// merged: z selects Wq/Wk/Wv -> Wt3 + z*E*E
__global__ __launch_bounds__(256) void transpose_cast3(const float* __restrict__ Wq,
                                                       const float* __restrict__ Wk,
                                                       const float* __restrict__ Wv,
                                                       bf16* __restrict__ Wt3) {
  int z = blockIdx.z;
  const float* W = (z == 0) ? Wq : (z == 1) ? Wk : Wv;
  transpose_body(W, Wt3 + (size_t)z * EMBED * EMBED);
}

// ---------------- pipelined GEMM core (R13-proven, the class optimum) ---------
// BM=128, BN=256, BK=64; 512 threads = 8 waves (2M x 4N), 64x64 per wave.
// Triple-buffered LDS (144 KB), prefetch depth 2, ONE barrier per K-tile,
// counted vmcnt(6) — never drains to 0 in steady state (T3+T4). XOR swizzle
// (T2, conflicts=0 measured). Tested-and-rejected variants: 128^2 2-phase,
// 128^2 1-barrier 2-slot (R14), 4-wave 64x128 (R10), direct-global A (R5),
// 256^2 2-slot (R19), XCD-panel swizzle (R18, no FETCH change). 36% MfmaUtil
// = the documented m97-class ceiling for this geometry.
// mode 1: rotary bf16 out (Q,K); 2: V-transposed bf16 out; 3: fp32 out.
__device__ __forceinline__ void gemm_body(const bf16* __restrict__ A,
                                          const bf16* __restrict__ Bt,
                                          void* __restrict__ Cout,
                                          int M, int N, int K, int mode,
                                          int bx, int by) {
  constexpr int BM = 128, BN = 256, BK = 64;
  __shared__ __align__(16) bf16 As[3][BM * BK];  // 3 x 16 KB
  __shared__ __align__(16) bf16 Bs[3][BN * BK];  // 3 x 32 KB
  int t = threadIdx.x;
  int lane = t & 63, w = t >> 6;
  int c16 = lane & 15, g4 = lane >> 4;
  int wm = w >> 2, wn = w & 3;
  int m0 = by * BM, n0 = bx * BN;
  int nt = K / BK;

  f32x4 acc[4][4] = {};

  auto stage = [&](int kt, int slot) {
    const bf16* Asrc = A + (size_t)m0 * K + kt * BK;
    const bf16* Bsrc = Bt + (size_t)n0 * K + kt * BK;
    bf16* Ad = As[slot];
    bf16* Bd = Bs[slot];
#pragma unroll
    for (int i = 0; i < 2; i++) {  // A: 1024 chunks / 512 threads
      int c = i * 512 + t;
      int row = c >> 3, col8 = c & 7;
      async_copy16(Asrc + (size_t)row * K + ((col8 ^ (row & 7)) * 8), Ad + c * 8);
    }
#pragma unroll
    for (int i = 0; i < 4; i++) {  // B: 2048 chunks / 512 threads
      int c = i * 512 + t;
      int row = c >> 3, col8 = c & 7;
      async_copy16(Bsrc + (size_t)row * K + ((col8 ^ (row & 7)) * 8), Bd + c * 8);
    }
  };

  // prologue: tiles 0 and 1 in flight; wait tile 0 (6 of 12 outstanding left)
  stage(0, 0);
  stage(1, 1);
  asm volatile("s_waitcnt vmcnt(6)" ::: "memory");
  __builtin_amdgcn_s_barrier();

  for (int kt = 0; kt < nt; kt++) {
    int slot = kt - (kt / 3) * 3;
    const bf16* Ab = As[slot];
    const bf16* Bb = Bs[slot];

    bf16x8 af[2][4], bfr[2][4];
#pragma unroll
    for (int kk = 0; kk < 2; kk++) {
#pragma unroll
      for (int fm = 0; fm < 4; fm++) {
        int row = wm * 64 + fm * 16 + c16;
        af[kk][fm] = *(const bf16x8*)(Ab + row * BK + (((kk * 4 + g4) ^ (row & 7)) * 8));
      }
#pragma unroll
      for (int fn = 0; fn < 4; fn++) {
        int row = wn * 64 + fn * 16 + c16;
        bfr[kk][fn] = *(const bf16x8*)(Bb + row * BK + (((kk * 4 + g4) ^ (row & 7)) * 8));
      }
    }
    if (kt + 2 < nt) {
      int s2 = (kt + 2) - ((kt + 2) / 3) * 3;
      stage(kt + 2, s2);
    }
    __builtin_amdgcn_s_setprio(1);
#pragma unroll
    for (int kk = 0; kk < 2; kk++)
#pragma unroll
      for (int fm = 0; fm < 4; fm++)
#pragma unroll
        for (int fn = 0; fn < 4; fn++)
          acc[fm][fn] = __builtin_amdgcn_mfma_f32_16x16x32_bf16(af[kk][fm], bfr[kk][fn],
                                                                acc[fm][fn], 0, 0, 0);
    __builtin_amdgcn_s_setprio(0);
    if (kt < nt - 2) {
      asm volatile("s_waitcnt vmcnt(6)" ::: "memory");
      __builtin_amdgcn_s_barrier();
    } else if (kt == nt - 2) {
      asm volatile("s_waitcnt vmcnt(0)" ::: "memory");
      __builtin_amdgcn_s_barrier();
    }
  }

  // epilogue (mode is block-uniform)
#pragma unroll
  for (int fm = 0; fm < 4; fm++) {
#pragma unroll
    for (int fn = 0; fn < 4; fn++) {
      int col = n0 + wn * 64 + fn * 16 + c16;
#pragma unroll
      for (int r = 0; r < 4; r++) {
        int row = m0 + wm * 64 + fm * 16 + g4 * 4 + r;
        float v = acc[fm][fn][r];
        if (mode == 1) {
          int d = col & (HDIM - 1);
          if (d < ROT) {  // wave-uniform: true iff wn==0
            float pv = __shfl_xor(v, 1);
            int jj = d >> 1;
            float invf = __expf(-0.28782313662425575f * (float)jj);
            float ang = (float)row * invf;
            float sa, ca;
            sincosf(ang, &sa, &ca);
            v = v * ca + pv * sa;  // reference has NO negation in rotate_every_two
          }
        }
        if (mode == 3) {
          ((float*)Cout)[(size_t)row * N + col] = v;
        } else if (mode == 2) {
          ((bf16*)Cout)[(size_t)col * M + row] = (bf16)v;
        } else {
          ((bf16*)Cout)[(size_t)row * N + col] = (bf16)v;
        }
      }
    }
  }
}

template <int MODE>
__global__ __launch_bounds__(512, 1) void gemm_pipe(const bf16* __restrict__ A,
                                                    const bf16* __restrict__ Bt,
                                                    void* __restrict__ Cout,
                                                    int M, int N, int K) {
  gemm_body(A, Bt, Cout, M, N, K, MODE, blockIdx.x, blockIdx.y);
}

// merged QKV GEMM: grid (16,16,3); z -> {weight, output, epilogue mode}.
// 768 blocks: CUs roll from Q tiles into K/V tiles (no per-kernel tail drain).
__global__ __launch_bounds__(512, 1) void gemm_qkv(const bf16* __restrict__ A,
                                                   const bf16* __restrict__ Wt3,
                                                   bf16* __restrict__ Qb,
                                                   bf16* __restrict__ Kb,
                                                   bf16* __restrict__ Vtb) {
  int z = blockIdx.z;
  const bf16* Bt = Wt3 + (size_t)z * EMBED * EMBED;
  void* out = (z == 0) ? (void*)Qb : (z == 1) ? (void*)Kb : (void*)Vtb;
  int mode = (z == 2) ? 2 : 1;
  gemm_body(A, Bt, out, SLEN, EMBED, EMBED, mode, blockIdx.x, blockIdx.y);
}

// ---------------- causal flash attention (R16-proven) -------------------------
// 512 blocks, 2/CU; balanced pairing: pair (b, b+256) sums to 33 iters; shares
// h = b&15 (same K/V L2 lines; 2 heads/XCD). Ping-pong single-buffered K/V:
// QK(t) | barrier A | stage K(t+1) | softmax | PV(t) | barrier B | stage V(t+1).
// XOR-swizzle, defer-max (T13), per-lane lrow (R11).
__global__ __launch_bounds__(256, 2) void attn_kernel(const bf16* __restrict__ Q,
                                                      const bf16* __restrict__ Kmat,
                                                      const bf16* __restrict__ Vt,
                                                      bf16* __restrict__ O) {
  __shared__ __align__(16) bf16 Ks[64 * 256];   // [kv_row][d], swizzled (32 KB)
  __shared__ __align__(16) bf16 Vs[64 * 256];   // [d][kv_row], swizzled (32 KB)
  __shared__ __align__(16) bf16 Pl[4][16 * 64]; // per-wave P, swizzled (8 KB)
  int t = threadIdx.x, lane = t & 63, w = t >> 6;
  int c16 = lane & 15, g4 = lane >> 4;
  int b = blockIdx.x;
  int bb = b & 255;
  int h = bb & 15;
  int k = bb >> 4;                       // 0..15
  int qt = (b >> 8) ? k : (31 - k);      // heavy half first; pair sums to 33
  int q0w = qt * 64 + w * 16;

  auto stageK = [&](int kt) {
#pragma unroll
    for (int j = 0; j < 8; j++) {
      int c = j * 256 + t;
      int row = c >> 5, col8 = c & 31;
      async_copy16(Kmat + (size_t)(kt * 64 + row) * EMBED + h * HDIM +
                       ((col8 ^ (row & 7)) * 8),
                   Ks + (size_t)c * 8);
    }
  };
  auto stageV = [&](int kt) {
#pragma unroll
    for (int j = 0; j < 8; j++) {
      int c = j * 256 + t;
      int row = c >> 3, col8 = c & 7;
      async_copy16(Vt + (size_t)(h * HDIM + row) * SLEN + kt * 64 +
                       ((col8 ^ (row & 7)) * 8),
                   Vs + (size_t)c * 8);
    }
  };

  bf16x8 qf[8];
  {
    const bf16* qp = Q + (size_t)(q0w + c16) * EMBED + h * HDIM + g4 * 8;
#pragma unroll
    for (int kk = 0; kk < 8; kk++) qf[kk] = *(const bf16x8*)(qp + kk * 32);
  }
  f32x4 acco[16] = {};
  float mrow[4], lrow[4];  // mrow row-uniform; lrow PER-LANE partial
#pragma unroll
  for (int r = 0; r < 4; r++) { mrow[r] = -1e30f; lrow[r] = 0.f; }

  stageK(0);
  stageV(0);
  __syncthreads();  // drain: K(0), V(0) resident

  for (int kt = 0; kt <= qt; kt++) {
    // ---- QK(t) from Ks ----
    f32x4 accs[4] = {};
    __builtin_amdgcn_s_setprio(1);
#pragma unroll
    for (int kk = 0; kk < 8; kk++) {
#pragma unroll
      for (int fn = 0; fn < 4; fn++) {
        int r = fn * 16 + c16;
        bf16x8 kf = *(const bf16x8*)(Ks + r * 256 + ((kk * 4 + g4) ^ (c16 & 7)) * 8);
        accs[fn] = __builtin_amdgcn_mfma_f32_16x16x32_bf16(qf[kk], kf, accs[fn], 0, 0, 0);
      }
    }
    __builtin_amdgcn_s_setprio(0);
    __syncthreads();  // barrier A: frees Ks; drains V(t) staging
    if (kt < qt) stageK(kt + 1);  // in flight under softmax + PV

    // ---- softmax ----
    float pm[4][4];
    bool diag = (kt == qt);
#pragma unroll
    for (int fn = 0; fn < 4; fn++)
#pragma unroll
      for (int r = 0; r < 4; r++) {
        float s = accs[fn][r] * 0.0625f;  // 1/sqrt(256); mask-before-scale == -1e30
        if (diag) {
          int kg = fn * 16 + c16;
          int qg = w * 16 + g4 * 4 + r;
          if (kg > qg) s = -1e30f;
        }
        pm[fn][r] = s;
      }
    float lmax[4];
#pragma unroll
    for (int r = 0; r < 4; r++)
      lmax[r] = fmaxf(fmaxf(pm[0][r], pm[1][r]), fmaxf(pm[2][r], pm[3][r]));
    bool need = false;
#pragma unroll
    for (int r = 0; r < 4; r++) need = need || (lmax[r] > mrow[r] + 8.0f);
    if (__any(need)) {  // rare: full max-reduce + rescale only here
#pragma unroll
      for (int r = 0; r < 4; r++) {
        float mx = lmax[r];
#pragma unroll
        for (int off = 1; off < 16; off <<= 1) mx = fmaxf(mx, __shfl_xor(mx, off));
        float mn = fmaxf(mrow[r], mx);
        float sc = __expf(mrow[r] - mn);
        mrow[r] = mn;
        lrow[r] *= sc;
#pragma unroll
        for (int fd = 0; fd < 16; fd++) acco[fd][r] *= sc;
      }
    }
#pragma unroll
    for (int fn = 0; fn < 4; fn++)
#pragma unroll
      for (int r = 0; r < 4; r++) {
        float p = __expf(pm[fn][r] - mrow[r]);
        pm[fn][r] = p;
        lrow[r] += p;
      }
#pragma unroll
    for (int fn = 0; fn < 4; fn++)
#pragma unroll
      for (int r = 0; r < 4; r++) {
        int q = g4 * 4 + r;
        int chunk = (fn * 2 + (c16 >> 3)) ^ (q & 7);
        Pl[w][q * 64 + chunk * 8 + (c16 & 7)] = (bf16)pm[fn][r];
      }
    // ---- PV(t) from Vs ----
    __builtin_amdgcn_s_setprio(1);
#pragma unroll
    for (int kk2 = 0; kk2 < 2; kk2++) {
      bf16x8 pf = *(const bf16x8*)(&Pl[w][c16 * 64 + ((kk2 * 4 + g4) ^ (c16 & 7)) * 8]);
#pragma unroll
      for (int fd = 0; fd < 16; fd++) {
        int rv = fd * 16 + c16;
        bf16x8 vf = *(const bf16x8*)(Vs + rv * 64 + ((kk2 * 4 + g4) ^ (c16 & 7)) * 8);
        acco[fd] = __builtin_amdgcn_mfma_f32_16x16x32_bf16(pf, vf, acco[fd], 0, 0, 0);
      }
    }
    __builtin_amdgcn_s_setprio(0);
    __syncthreads();  // barrier B: frees Vs; drains K(t+1) staging
    if (kt < qt) stageV(kt + 1);  // in flight under next QK
  }
  // epilogue: one row-wide sum-reduce of the per-lane lrow partials
  float inv[4];
#pragma unroll
  for (int r = 0; r < 4; r++) {
    float s = lrow[r];
#pragma unroll
    for (int off = 1; off < 16; off <<= 1) s += __shfl_xor(s, off);
    inv[r] = 1.0f / s;
  }
#pragma unroll
  for (int fd = 0; fd < 16; fd++)
#pragma unroll
    for (int r = 0; r < 4; r++) {
      int qg = q0w + g4 * 4 + r;
      int col = h * HDIM + fd * 16 + c16;
      O[(size_t)qg * EMBED + col] = (bf16)(acco[fd][r] * inv[r]);
    }
}

extern "C" void kernel_launch(void* const* d_in, const int* in_sizes, int n_in,
                              void* d_out, int out_size, void* d_ws, size_t ws_size,
                              hipStream_t stream) {
  const float* hidden = (const float*)d_in[0];
  const float* Wq = (const float*)d_in[1];
  const float* Wk = (const float*)d_in[2];
  const float* Wv = (const float*)d_in[3];
  const float* Wo = (const float*)d_in[4];
  float* out = (float*)d_out;

  char* ws = (char*)d_ws;
  const size_t SZ_H = (size_t)SLEN * EMBED * 2;   // 16 MiB
  const size_t SZ_W = (size_t)EMBED * EMBED * 2;  // 32 MiB

  dim3 tgrid(EMBED / 64, EMBED / 64);
  dim3 ggrid(EMBED / 256, SLEN / 128);  // 16 x 16 = 256 blocks

  if (ws_size >= 5 * SZ_H + 3 * SZ_W) {
    // merged path (176 MiB, R17-proven best: 450.5 us): 3-way transpose +
    // one 768-block QKV GEMM.
    bf16* h_bf = (bf16*)ws;
    bf16* Wt3  = (bf16*)(ws + SZ_H);
    bf16* Qb   = (bf16*)(ws + SZ_H + 3 * SZ_W);
    bf16* Kb   = (bf16*)(ws + 2 * SZ_H + 3 * SZ_W);
    bf16* Vtb  = (bf16*)(ws + 3 * SZ_H + 3 * SZ_W);
    bf16* Ob   = (bf16*)(ws + 4 * SZ_H + 3 * SZ_W);

    cast_kernel<<<(SLEN * EMBED / 4 + 255) / 256, 256, 0, stream>>>(
        hidden, h_bf, SLEN * EMBED / 4);
    transpose_cast3<<<dim3(EMBED / 64, EMBED / 64, 3), 256, 0, stream>>>(Wq, Wk,
                                                                         Wv, Wt3);
    gemm_qkv<<<dim3(EMBED / 256, SLEN / 128, 3), 512, 0, stream>>>(h_bf, Wt3, Qb,
                                                                   Kb, Vtb);
    attn_kernel<<<dim3(512), 256, 0, stream>>>(Qb, Kb, Vtb, Ob);
    transpose_cast<<<tgrid, 256, 0, stream>>>(Wo, Wt3);
    gemm_pipe<3><<<ggrid, 512, 0, stream>>>(Ob, Wt3, out, SLEN, EMBED, EMBED);
    return;
  }

  // fallback (112 MiB, per-GEMM sequence)
  if (ws_size < 5 * SZ_H + SZ_W) return;
  bf16* h_bf = (bf16*)ws;
  bf16* Wt   = (bf16*)(ws + SZ_H);
  bf16* Qb   = (bf16*)(ws + SZ_H + SZ_W);
  bf16* Kb   = (bf16*)(ws + 2 * SZ_H + SZ_W);
  bf16* Vtb  = (bf16*)(ws + 3 * SZ_H + SZ_W);
  bf16* Ob   = (bf16*)(ws + 4 * SZ_H + SZ_W);

  cast_kernel<<<(SLEN * EMBED / 4 + 255) / 256, 256, 0, stream>>>(hidden, h_bf,
                                                                  SLEN * EMBED / 4);
  transpose_cast<<<tgrid, 256, 0, stream>>>(Wq, Wt);
  gemm_pipe<1><<<ggrid, 512, 0, stream>>>(h_bf, Wt, Qb, SLEN, EMBED, EMBED);
  transpose_cast<<<tgrid, 256, 0, stream>>>(Wk, Wt);
  gemm_pipe<1><<<ggrid, 512, 0, stream>>>(h_bf, Wt, Kb, SLEN, EMBED, EMBED);
  transpose_cast<<<tgrid, 256, 0, stream>>>(Wv, Wt);
  gemm_pipe<2><<<ggrid, 512, 0, stream>>>(h_bf, Wt, Vtb, SLEN, EMBED, EMBED);
  attn_kernel<<<dim3(512), 256, 0, stream>>>(Qb, Kb, Vtb, Ob);
  transpose_cast<<<tgrid, 256, 0, stream>>>(Wo, Wt);
  gemm_pipe<3><<<ggrid, 512, 0, stream>>>(Ob, Wt, out, SLEN, EMBED, EMBED);
}